// Round 1
// baseline (366.810 us; speedup 1.0000x reference)
//
#include <hip/hip_runtime.h>

// TinyRecursiveModel fused kernel, v1 (MFMA bf16, fp32 residual/LN).
// Transposed formulation: D[feature][batchrow] = W_tile x h^T_tile via
// mfma_f32_16x16x32_bf16. Weights live in VGPRs (loaded once), h/tmp live in
// swizzled bf16 LDS, residual h stays fp32 in registers (D layout).

using bf16x4 = __attribute__((ext_vector_type(4))) short;
using bf16x8 = __attribute__((ext_vector_type(8))) short;
using f32x4  = __attribute__((ext_vector_type(4))) float;

#define DI __device__ __forceinline__

namespace {

constexpr int TB    = 512;   // threads per block (8 waves: 2 feature-halves x 4 row-quarters)
constexpr int ROWS  = 64;    // batch rows per block
constexpr int NSTEP = 16;
constexpr float EPS = 1e-5f;

DI short f2bf(float x) {            // f32 -> bf16 round-to-nearest-even
  unsigned u = __float_as_uint(x);
  u += 0x7fffu + ((u >> 16) & 1u);
  return (short)(u >> 16);
}

struct WF { bf16x8 f[2][2]; };      // weight frags [t'][k-step]

DI int swz(int row, int colbyte) {  // 128B-stride row, XOR-swizzled (G4)
  return row * 128 + (colbyte ^ ((row & 7) << 4));
}

// Load one A-frag (16B = 8 bf16) of a 64x64 f32 row-major weight matrix.
DI bf16x8 ldwf(const float* W, int row, int k0) {
  const float* p = W + row * 64 + k0;
  f32x4 a = *(const f32x4*)p;
  f32x4 b = *(const f32x4*)(p + 4);
  bf16x8 r;
  r[0] = f2bf(a[0]); r[1] = f2bf(a[1]); r[2] = f2bf(a[2]); r[3] = f2bf(a[3]);
  r[4] = f2bf(b[0]); r[5] = f2bf(b[1]); r[6] = f2bf(b[2]); r[7] = f2bf(b[3]);
  return r;
}

struct Smem {
  char  hlds[8192];        // h,  64 rows x 64 bf16, swizzled
  char  tlds[8192];        // v / ff1 buffer, same layout
  char  xstage[8192];      // input phase: 64 rows x 32 bf16 (128B stride)
  float params[2 * 8 * 64];// per layer: bv, bo, b1, b2, g1, be1, g2, be2
  float2 lnbuf[128];       // LN partial (sum, sumsq) per [mh][row]; reused as obuf
};

// y^T tile = W x h^T :  2 MFMAs per k-step per feature-half.
DI void mm(const char* src, const WF& w, f32x4 (&acc)[2], int c, int g) {
#pragma unroll
  for (int s = 0; s < 2; ++s) {
    bf16x8 b = *(const bf16x8*)(src + swz(c, 64 * s + 16 * g));
#pragma unroll
    for (int tp = 0; tp < 2; ++tp)
      acc[tp] = __builtin_amdgcn_mfma_f32_16x16x32_bf16(w.f[tp][s], b, acc[tp], 0, 0, 0);
  }
}

DI void addbias(const float* vec, f32x4 (&acc)[2], int mh, int g) {
#pragma unroll
  for (int tp = 0; tp < 2; ++tp) {
    f32x4 bv = *(const f32x4*)(vec + 16 * (2 * mh + tp) + 4 * g);
#pragma unroll
    for (int r = 0; r < 4; ++r) acc[tp][r] += bv[r];
  }
}

// Write D-layout values (4 contiguous features per t') as bf16 into swizzled LDS.
DI void dwrite(char* dst, const f32x4 (&v)[2], int c, int g, int mh, bool relu) {
#pragma unroll
  for (int tp = 0; tp < 2; ++tp) {
    int t = 2 * mh + tp;
    bf16x4 o;
#pragma unroll
    for (int r = 0; r < 4; ++r) {
      float x = v[tp][r];
      if (relu) x = fmaxf(x, 0.f);
      o[r] = f2bf(x);
    }
    *(bf16x4*)(dst + swz(c, 32 * t + 8 * g)) = o;
  }
}

// LayerNorm over 64 features of batch row c; features split across wave pair (mh).
DI void lnorm(f32x4 (&h)[2], const float* gvec, const float* bvec, Smem* sm,
              int c, int g, int mh, int lane) {
  float s = 0.f, q = 0.f;
#pragma unroll
  for (int tp = 0; tp < 2; ++tp)
#pragma unroll
    for (int r = 0; r < 4; ++r) { float x = h[tp][r]; s += x; q += x * x; }
  s += __shfl_xor(s, 16); q += __shfl_xor(q, 16);
  s += __shfl_xor(s, 32); q += __shfl_xor(q, 32);
  if (lane < 16) sm->lnbuf[mh * 64 + c] = make_float2(s, q);
  __syncthreads();
  float2 o = sm->lnbuf[(1 - mh) * 64 + c];
  float fs = s + o.x, fq = q + o.y;
  float mean = fs * 0.015625f;
  float var  = fq * 0.015625f - mean * mean;
  float rs   = rsqrtf(var + EPS);
#pragma unroll
  for (int tp = 0; tp < 2; ++tp) {
    f32x4 gv = *(const f32x4*)(gvec + 16 * (2 * mh + tp) + 4 * g);
    f32x4 bv = *(const f32x4*)(bvec + 16 * (2 * mh + tp) + 4 * g);
#pragma unroll
    for (int r = 0; r < 4; ++r)
      h[tp][r] = (h[tp][r] - mean) * rs * gv[r] + bv[r];
  }
}

DI void layer(f32x4 (&hreg)[2], const WF& wv, const WF& wo, const WF& w1, const WF& w2,
              const float* pp, Smem* sm, int c, int g, int mh, int lane) {
  // ---- v = h @ Wv^T + bv ----
  f32x4 acc[2] = {f32x4{0, 0, 0, 0}, f32x4{0, 0, 0, 0}};
  mm(sm->hlds, wv, acc, c, g);
  addbias(pp + 0 * 64, acc, mh, g);
  dwrite(sm->tlds, acc, c, g, mh, false);
  __syncthreads();                              // tlds RAW
  // ---- sa = v @ Wo^T + bo ; h += sa ; LN1 ----
  f32x4 a2[2] = {f32x4{0, 0, 0, 0}, f32x4{0, 0, 0, 0}};
  mm(sm->tlds, wo, a2, c, g);
  addbias(pp + 1 * 64, a2, mh, g);
#pragma unroll
  for (int tp = 0; tp < 2; ++tp)
#pragma unroll
    for (int r = 0; r < 4; ++r) hreg[tp][r] += a2[tp][r];
  lnorm(hreg, pp + 4 * 64, pp + 5 * 64, sm, c, g, mh, lane);  // has own barrier
  dwrite(sm->hlds, hreg, c, g, mh, false);
  __syncthreads();                              // hlds RAW
  // ---- ff1 = relu(h @ W1^T + b1) ----
  f32x4 a3[2] = {f32x4{0, 0, 0, 0}, f32x4{0, 0, 0, 0}};
  mm(sm->hlds, w1, a3, c, g);
  addbias(pp + 2 * 64, a3, mh, g);
  dwrite(sm->tlds, a3, c, g, mh, true);
  __syncthreads();                              // tlds RAW
  // ---- ff2 ; h += ; LN2 ----
  f32x4 a4[2] = {f32x4{0, 0, 0, 0}, f32x4{0, 0, 0, 0}};
  mm(sm->tlds, w2, a4, c, g);
  addbias(pp + 3 * 64, a4, mh, g);
#pragma unroll
  for (int tp = 0; tp < 2; ++tp)
#pragma unroll
    for (int r = 0; r < 4; ++r) hreg[tp][r] += a4[tp][r];
  lnorm(hreg, pp + 6 * 64, pp + 7 * 64, sm, c, g, mh, lane);  // has own barrier
  dwrite(sm->hlds, hreg, c, g, mh, false);
  __syncthreads();                              // hlds RAW for next layer
}

__global__ __launch_bounds__(TB, 2) void trm_kernel(
    const float* __restrict__ x, const float* __restrict__ input_w,
    const float* __restrict__ input_b, const float* __restrict__ Wqkv,
    const float* __restrict__ bqkv, const float* __restrict__ Wo,
    const float* __restrict__ bo, const float* __restrict__ ln1_g,
    const float* __restrict__ ln1_b, const float* __restrict__ W1,
    const float* __restrict__ b1, const float* __restrict__ W2,
    const float* __restrict__ b2, const float* __restrict__ ln2_g,
    const float* __restrict__ ln2_b, const float* __restrict__ out_w,
    const float* __restrict__ out_b, float* __restrict__ out) {
  __shared__ Smem sm;
  const int tid  = threadIdx.x;
  const int w    = tid >> 6, lane = tid & 63;
  const int l15  = lane & 15, g = lane >> 4;
  const int mh   = w >> 2, nq = w & 3;   // feature half / row quarter
  const int c    = 16 * nq + l15;        // block-local batch row of this lane
  const int rowbase = blockIdx.x * ROWS;

  // ---- stage small per-layer param vectors into LDS ----
  for (int e = tid; e < 2 * 8 * 64; e += TB) {
    int l = e >> 9, v = (e >> 6) & 7, j = e & 63;
    const float* src;
    switch (v) {
      case 0:  src = bqkv + l * 192 + 128; break;   // bv = bqkv[l, 2D:3D]
      case 1:  src = bo    + l * 64; break;
      case 2:  src = b1    + l * 64; break;
      case 3:  src = b2    + l * 64; break;
      case 4:  src = ln1_g + l * 64; break;
      case 5:  src = ln1_b + l * 64; break;
      case 6:  src = ln2_g + l * 64; break;
      default: src = ln2_b + l * 64; break;
    }
    sm.params[e] = src[j];
  }

  // ---- preload all weight fragments into registers (128 VGPR/wave) ----
  WF wv0, wo0, w10, w20, wv1, wo1, w11, w21;
#pragma unroll
  for (int tp = 0; tp < 2; ++tp)
#pragma unroll
    for (int s = 0; s < 2; ++s) {
      int row = 16 * (2 * mh + tp) + l15, k0 = 32 * s + 8 * g;
      wv0.f[tp][s] = ldwf(Wqkv + (0 * 192 + 128) * 64, row, k0);
      wo0.f[tp][s] = ldwf(Wo + 0 * 4096, row, k0);
      w10.f[tp][s] = ldwf(W1 + 0 * 4096, row, k0);
      w20.f[tp][s] = ldwf(W2 + 0 * 4096, row, k0);
      wv1.f[tp][s] = ldwf(Wqkv + (1 * 192 + 128) * 64, row, k0);
      wo1.f[tp][s] = ldwf(Wo + 1 * 4096, row, k0);
      w11.f[tp][s] = ldwf(W1 + 1 * 4096, row, k0);
      w21.f[tp][s] = ldwf(W2 + 1 * 4096, row, k0);
    }

  // ---- input projection: h = x @ input_w^T + input_b  (K=200, 7 chunks of 32) ----
  f32x4 iacc[2] = {f32x4{0, 0, 0, 0}, f32x4{0, 0, 0, 0}};
  for (int s7 = 0; s7 < 7; ++s7) {
    {  // stage 64x32 f32 chunk of x as bf16 (zero-padded past k=200)
      int r = tid >> 3, c0 = (tid & 7) * 4;
      int k0 = 32 * s7 + c0;
      f32x4 v = {0.f, 0.f, 0.f, 0.f};
      if (k0 < 200) v = *(const f32x4*)(x + (size_t)(rowbase + r) * 200 + k0);
      bf16x4 o;
      o[0] = f2bf(v[0]); o[1] = f2bf(v[1]); o[2] = f2bf(v[2]); o[3] = f2bf(v[3]);
      *(bf16x4*)(sm.xstage + swz(r, c0 * 2)) = o;
    }
    __syncthreads();
    bf16x8 bfrag = *(const bf16x8*)(sm.xstage + swz(c, 16 * g));
#pragma unroll
    for (int tp = 0; tp < 2; ++tp) {
      int row = 16 * (2 * mh + tp) + l15;
      int k0 = 32 * s7 + 8 * g;
      bf16x8 afrag;
#pragma unroll
      for (int j = 0; j < 8; ++j) {
        int kk = k0 + j;
        afrag[j] = (kk < 200) ? f2bf(input_w[row * 200 + kk]) : (short)0;
      }
      iacc[tp] = __builtin_amdgcn_mfma_f32_16x16x32_bf16(afrag, bfrag, iacc[tp], 0, 0, 0);
    }
    __syncthreads();
  }
  f32x4 hreg[2];
#pragma unroll
  for (int tp = 0; tp < 2; ++tp) {
    f32x4 ib = *(const f32x4*)(input_b + 16 * (2 * mh + tp) + 4 * g);
#pragma unroll
    for (int r = 0; r < 4; ++r) hreg[tp][r] = iacc[tp][r] + ib[r];
  }
  dwrite(sm.hlds, hreg, c, g, mh, false);
  __syncthreads();

  // ---- recurrence: 16 steps x 2 layers ----
  for (int step = 0; step < NSTEP; ++step) {
    layer(hreg, wv0, wo0, w10, w20, sm.params,          &sm, c, g, mh, lane);
    layer(hreg, wv1, wo1, w11, w21, sm.params + 8 * 64, &sm, c, g, mh, lane);
  }

  // ---- out = (h @ out_w^T + out_b)[:, 0] ----
  float part = 0.f;
#pragma unroll
  for (int tp = 0; tp < 2; ++tp) {
    f32x4 owv = *(const f32x4*)(out_w + 16 * (2 * mh + tp) + 4 * g);
#pragma unroll
    for (int r = 0; r < 4; ++r) part += hreg[tp][r] * owv[r];
  }
  part += __shfl_xor(part, 16);
  part += __shfl_xor(part, 32);
  float* obuf = (float*)sm.lnbuf;  // safe to reuse after last layer barrier
  if (lane < 16) obuf[w * 16 + l15] = part;
  __syncthreads();
  if (mh == 0 && lane < 16) {
    float tot = obuf[nq * 16 + l15] + obuf[(4 + nq) * 16 + l15] + out_b[0];
    out[rowbase + c] = tot;
  }
}

}  // namespace

extern "C" void kernel_launch(void* const* d_in, const int* in_sizes, int n_in,
                              void* d_out, int out_size, void* d_ws, size_t ws_size,
                              hipStream_t stream) {
  const float* x       = (const float*)d_in[0];
  const float* input_w = (const float*)d_in[1];
  const float* input_b = (const float*)d_in[2];
  const float* Wqkv    = (const float*)d_in[3];
  const float* bqkv    = (const float*)d_in[4];
  const float* Wo      = (const float*)d_in[5];
  const float* bo      = (const float*)d_in[6];
  const float* ln1_g   = (const float*)d_in[7];
  const float* ln1_b   = (const float*)d_in[8];
  const float* W1      = (const float*)d_in[9];
  const float* b1      = (const float*)d_in[10];
  const float* W2      = (const float*)d_in[11];
  const float* b2      = (const float*)d_in[12];
  const float* ln2_g   = (const float*)d_in[13];
  const float* ln2_b   = (const float*)d_in[14];
  const float* out_w   = (const float*)d_in[15];
  const float* out_b   = (const float*)d_in[16];
  float* out = (float*)d_out;

  dim3 grid(65536 / ROWS), block(TB);
  hipLaunchKernelGGL(trm_kernel, grid, block, 0, stream,
                     x, input_w, input_b, Wqkv, bqkv, Wo, bo, ln1_g, ln1_b,
                     W1, b1, W2, b2, ln2_g, ln2_b, out_w, out_b, out);
}

// Round 2
// 192.836 us; speedup vs baseline: 1.9022x; 1.9022x over previous
//
#include <hip/hip_runtime.h>

// TinyRecursiveModel fused kernel, v2.
// - Precompute kernel: W_vo = Wo @ Wv, b_vo = Wo @ bv + bo (fp32, into d_ws).
//   Removes the v->sa matmul pair (4 matmuls/layer -> 3).
// - Main kernel: each wave owns 16 batch rows and ALL 64 features
//   (4 tp-fragments). LayerNorm = 2 shfl_xor. The h/t bf16 staging buffer is
//   wave-private LDS -> ZERO __syncthreads in the 32-layer recurrence.
// - Weights: W_vo(l0,l1), W1(l0), W2(l0) as bf16 A-frags in VGPRs; W1(l1),
//   W2(l1) in swizzled LDS. Biases enter as MFMA C-in (residual folded in).

using bf16x8 = __attribute__((ext_vector_type(8))) short;
using f32x4  = __attribute__((ext_vector_type(4))) float;

#define DI __device__ __forceinline__

namespace {

constexpr float EPS = 1e-5f;

DI unsigned pack_bf2(float a, float b) {  // two f32 -> packed bf16 pair (RNE)
  unsigned ua = __float_as_uint(a), ub = __float_as_uint(b);
  ua += 0x7fffu + ((ua >> 16) & 1u);
  ub += 0x7fffu + ((ub >> 16) & 1u);
  return (ub & 0xffff0000u) | (ua >> 16);
}

DI bf16x8 cvt8(f32x4 a, f32x4 b) {  // 8 f32 -> bf16x8
  union { unsigned u[4]; bf16x8 h; } r;
  r.u[0] = pack_bf2(a[0], a[1]);
  r.u[1] = pack_bf2(a[2], a[3]);
  r.u[2] = pack_bf2(b[0], b[1]);
  r.u[3] = pack_bf2(b[2], b[3]);
  return r.h;
}

DI int swz(int row, int colbyte) {  // 128B-stride rows, XOR bank swizzle
  return row * 128 + (colbyte ^ ((row & 7) << 4));
}

DI void ldsfence() { asm volatile("s_waitcnt lgkmcnt(0)" ::: "memory"); }

struct WFrag { bf16x8 f[4][2]; };  // [tp][kstep] A-frags of a 64x64 matrix

DI WFrag loadW(const float* W, int l15, int g) {  // f32 row-major 64x64
  WFrag w;
#pragma unroll
  for (int tp = 0; tp < 4; ++tp)
#pragma unroll
    for (int s = 0; s < 2; ++s) {
      const float* p = W + (16 * tp + l15) * 64 + 32 * s + 8 * g;
      w.f[tp][s] = cvt8(*(const f32x4*)p, *(const f32x4*)(p + 4));
    }
  return w;
}

DI void mmapply(const WFrag& w, bf16x8 b0, bf16x8 b1, f32x4 (&acc)[4]) {
#pragma unroll
  for (int tp = 0; tp < 4; ++tp) {
    acc[tp] = __builtin_amdgcn_mfma_f32_16x16x32_bf16(w.f[tp][0], b0, acc[tp], 0, 0, 0);
    acc[tp] = __builtin_amdgcn_mfma_f32_16x16x32_bf16(w.f[tp][1], b1, acc[tp], 0, 0, 0);
  }
}

DI void mmapply_lds(const short* wl, bf16x8 b0, bf16x8 b1, f32x4 (&acc)[4],
                    int l15, int g) {
  const char* base = (const char*)wl;
#pragma unroll
  for (int tp = 0; tp < 4; ++tp) {
    bf16x8 a0 = *(const bf16x8*)(base + swz(16 * tp + l15, 16 * g));
    bf16x8 a1 = *(const bf16x8*)(base + swz(16 * tp + l15, 64 + 16 * g));
    acc[tp] = __builtin_amdgcn_mfma_f32_16x16x32_bf16(a0, b0, acc[tp], 0, 0, 0);
    acc[tp] = __builtin_amdgcn_mfma_f32_16x16x32_bf16(a1, b1, acc[tp], 0, 0, 0);
  }
}

DI void regread(const char* reg, int l15, int g, bf16x8& b0, bf16x8& b1) {
  b0 = *(const bf16x8*)(reg + swz(l15, 16 * g));
  b1 = *(const bf16x8*)(reg + swz(l15, 64 + 16 * g));
}

template <bool RELU>
DI void regwrite(char* reg, const f32x4 (&v)[4], int l15, int g) {
#pragma unroll
  for (int tp = 0; tp < 4; ++tp) {
    float x0 = v[tp][0], x1 = v[tp][1], x2 = v[tp][2], x3 = v[tp][3];
    if (RELU) {
      x0 = fmaxf(x0, 0.f); x1 = fmaxf(x1, 0.f);
      x2 = fmaxf(x2, 0.f); x3 = fmaxf(x3, 0.f);
    }
    uint2 p;
    p.x = pack_bf2(x0, x1);
    p.y = pack_bf2(x2, x3);
    *(uint2*)(reg + swz(l15, 32 * tp + 8 * g)) = p;
  }
}

DI void lnorm(const f32x4 (&a)[4], const float* gp, const float* bp, int g,
              f32x4 (&h)[4]) {
  float s = 0.f, q = 0.f;
#pragma unroll
  for (int tp = 0; tp < 4; ++tp)
#pragma unroll
    for (int r = 0; r < 4; ++r) { float x = a[tp][r]; s += x; q = fmaf(x, x, q); }
  s += __shfl_xor(s, 16); q += __shfl_xor(q, 16);
  s += __shfl_xor(s, 32); q += __shfl_xor(q, 32);
  float mean = s * 0.015625f;
  float var  = fmaf(q, 0.015625f, -mean * mean);
  float rs   = rsqrtf(var + EPS);
#pragma unroll
  for (int tp = 0; tp < 4; ++tp) {
    f32x4 gg = *(const f32x4*)(gp + 16 * tp + 4 * g);
    f32x4 bb = *(const f32x4*)(bp + 16 * tp + 4 * g);
#pragma unroll
    for (int r = 0; r < 4; ++r)
      h[tp][r] = fmaf((a[tp][r] - mean) * rs, gg[r], bb[r]);
  }
}

struct alignas(16) Smem {
  short w1l1[4096];          // W1 layer1, bf16, swizzled A-frag layout
  short w2l1[4096];          // W2 layer1
  float params[2 * 7 * 64];  // [layer][bvo,b1,b2,g1,be1,g2,be2][64]
  char  region[4][2048];     // per-wave h/t staging (16 rows x 64 bf16, swz)
};

template <bool FFLDS>
DI void do_layer(f32x4 (&h)[4], const WFrag& wvo, const WFrag* w1r,
                 const WFrag* w2r, const short* w1l, const short* w2l,
                 const float* prm, char* reg, int l15, int g) {
  // ---- h + sa : acc = (h + b_vo) + W_vo @ h^T ----
  f32x4 acc[4];
#pragma unroll
  for (int tp = 0; tp < 4; ++tp)
    acc[tp] = h[tp] + *(const f32x4*)(prm + 0 * 64 + 16 * tp + 4 * g);
  bf16x8 b0, b1;
  regread(reg, l15, g, b0, b1);
  mmapply(wvo, b0, b1, acc);
  lnorm(acc, prm + 3 * 64, prm + 4 * 64, g, h);   // h = LN1(...)
  regwrite<false>(reg, h, l15, g);
  ldsfence();
  // ---- t = relu(W1 @ h^T + b1) ----
#pragma unroll
  for (int tp = 0; tp < 4; ++tp)
    acc[tp] = *(const f32x4*)(prm + 1 * 64 + 16 * tp + 4 * g);
  regread(reg, l15, g, b0, b1);
  if (FFLDS) mmapply_lds(w1l, b0, b1, acc, l15, g);
  else       mmapply(*w1r, b0, b1, acc);
  regwrite<true>(reg, acc, l15, g);
  ldsfence();
  // ---- h + ff : a2 = (h + b2) + W2 @ t^T ----
  f32x4 a2[4];
#pragma unroll
  for (int tp = 0; tp < 4; ++tp)
    a2[tp] = h[tp] + *(const f32x4*)(prm + 2 * 64 + 16 * tp + 4 * g);
  regread(reg, l15, g, b0, b1);
  if (FFLDS) mmapply_lds(w2l, b0, b1, a2, l15, g);
  else       mmapply(*w2r, b0, b1, a2);
  lnorm(a2, prm + 5 * 64, prm + 6 * 64, g, h);    // h = LN2(...)
  regwrite<false>(reg, h, l15, g);
  ldsfence();
}

// ---------- precompute: W_vo = Wo @ Wv, b_vo = Wo @ bv + bo ----------
__global__ __launch_bounds__(256) void precompute_kernel(
    const float* __restrict__ Wqkv, const float* __restrict__ bqkv,
    const float* __restrict__ Wo, const float* __restrict__ bo,
    float* __restrict__ ws) {
  __shared__ float wv[4096];
  __shared__ float wo[4096];
  const int l = blockIdx.x;
  const float* Wv  = Wqkv + l * (192 * 64) + 128 * 64;
  const float* WoL = Wo + l * 4096;
  for (int e = threadIdx.x; e < 4096; e += 256) { wv[e] = Wv[e]; wo[e] = WoL[e]; }
  __syncthreads();
  float* wvo = ws + l * 4096;
  const int i = threadIdx.x >> 2, j0 = (threadIdx.x & 3) * 16;
  float acc[16];
#pragma unroll
  for (int jj = 0; jj < 16; ++jj) acc[jj] = 0.f;
  for (int k = 0; k < 64; ++k) {
    float a = wo[i * 64 + k];
#pragma unroll
    for (int jj = 0; jj < 16; ++jj) acc[jj] = fmaf(a, wv[k * 64 + j0 + jj], acc[jj]);
  }
#pragma unroll
  for (int jj = 0; jj < 16; ++jj) wvo[i * 64 + j0 + jj] = acc[jj];
  if (threadIdx.x < 64) {
    const int i2 = threadIdx.x;
    const float* bv = bqkv + l * 192 + 128;
    float s = bo[l * 64 + i2];
    for (int k = 0; k < 64; ++k) s = fmaf(wo[i2 * 64 + k], bv[k], s);
    ws[2 * 4096 + l * 64 + i2] = s;
  }
}

// ---------- main fused kernel ----------
__global__ __launch_bounds__(256, 2) void trm2_kernel(
    const float* __restrict__ x, const float* __restrict__ input_w,
    const float* __restrict__ input_b, const float* __restrict__ W1,
    const float* __restrict__ b1, const float* __restrict__ W2,
    const float* __restrict__ b2, const float* __restrict__ ln1_g,
    const float* __restrict__ ln1_b, const float* __restrict__ ln2_g,
    const float* __restrict__ ln2_b, const float* __restrict__ out_w,
    const float* __restrict__ out_b, const float* __restrict__ ws,
    float* __restrict__ out) {
  __shared__ Smem sm;
  const int tid = threadIdx.x;
  const int w = tid >> 6, lane = tid & 63;
  const int l15 = lane & 15, g = lane >> 4;
  const int rowbase = blockIdx.x * 64 + w * 16;
  char* reg = sm.region[w];

  // ---- cooperative staging: W1/W2 of layer 1 as swizzled bf16 ----
  for (int e = tid; e < 512; e += 256) {
    int row = e >> 3, c0 = (e & 7) * 8;
    const float* p1 = W1 + 4096 + row * 64 + c0;
    const float* p2 = W2 + 4096 + row * 64 + c0;
    *(bf16x8*)((char*)sm.w1l1 + swz(row, 2 * c0)) =
        cvt8(*(const f32x4*)p1, *(const f32x4*)(p1 + 4));
    *(bf16x8*)((char*)sm.w2l1 + swz(row, 2 * c0)) =
        cvt8(*(const f32x4*)p2, *(const f32x4*)(p2 + 4));
  }
  // ---- stage per-layer param vectors ----
  for (int e = tid; e < 896; e += 256) {
    int l = e / 448, r = e % 448, v = r >> 6, j = r & 63;
    const float* src;
    switch (v) {
      case 0:  src = ws + 2 * 4096 + l * 64; break;  // b_vo
      case 1:  src = b1 + l * 64; break;
      case 2:  src = b2 + l * 64; break;
      case 3:  src = ln1_g + l * 64; break;
      case 4:  src = ln1_b + l * 64; break;
      case 5:  src = ln2_g + l * 64; break;
      default: src = ln2_b + l * 64; break;
    }
    sm.params[l * 448 + v * 64 + j] = src[j];
  }

  // ---- register weights: W_vo(0,1), W1(0), W2(0) ----
  WFrag wvo0 = loadW(ws, l15, g);
  WFrag wvo1 = loadW(ws + 4096, l15, g);
  WFrag w1r  = loadW(W1, l15, g);
  WFrag w2r  = loadW(W2, l15, g);

  // ---- input projection: h = x @ input_w^T + input_b (K=200) ----
  f32x4 acc[4];
#pragma unroll
  for (int tp = 0; tp < 4; ++tp)
    acc[tp] = *(const f32x4*)(input_b + 16 * tp + 4 * g);
  const float* xrow = x + (size_t)(rowbase + l15) * 200;
  const f32x4 zero = {0.f, 0.f, 0.f, 0.f};
  for (int s7 = 0; s7 < 7; ++s7) {
    int kb = 32 * s7 + 8 * g;
    f32x4 xa = (kb < 200) ? *(const f32x4*)(xrow + kb) : zero;
    f32x4 xb = (kb + 4 < 200) ? *(const f32x4*)(xrow + kb + 4) : zero;
    bf16x8 bfrag = cvt8(xa, xb);
#pragma unroll
    for (int tp = 0; tp < 4; ++tp) {
      const float* wr = input_w + (16 * tp + l15) * 200;
      f32x4 wa = (kb < 200) ? *(const f32x4*)(wr + kb) : zero;
      f32x4 wb = (kb + 4 < 200) ? *(const f32x4*)(wr + kb + 4) : zero;
      acc[tp] = __builtin_amdgcn_mfma_f32_16x16x32_bf16(cvt8(wa, wb), bfrag,
                                                        acc[tp], 0, 0, 0);
    }
  }
  f32x4 h[4];
#pragma unroll
  for (int tp = 0; tp < 4; ++tp) h[tp] = acc[tp];
  regwrite<false>(reg, h, l15, g);
  ldsfence();
  __syncthreads();  // staging (w1l1/w2l1/params) ready; the ONLY block barrier

  // ---- recurrence: 16 steps x 2 layers, zero barriers ----
#pragma unroll 1
  for (int step = 0; step < 16; ++step) {
    do_layer<false>(h, wvo0, &w1r, &w2r, nullptr, nullptr, sm.params, reg, l15, g);
    do_layer<true>(h, wvo1, nullptr, nullptr, sm.w1l1, sm.w2l1,
                   sm.params + 448, reg, l15, g);
  }

  // ---- out = h . out_w + out_b ----
  float part = 0.f;
#pragma unroll
  for (int tp = 0; tp < 4; ++tp) {
    f32x4 ow = *(const f32x4*)(out_w + 16 * tp + 4 * g);
#pragma unroll
    for (int r = 0; r < 4; ++r) part = fmaf(h[tp][r], ow[r], part);
  }
  part += __shfl_xor(part, 16);
  part += __shfl_xor(part, 32);
  if (lane < 16) out[rowbase + l15] = part + out_b[0];
}

}  // namespace

extern "C" void kernel_launch(void* const* d_in, const int* in_sizes, int n_in,
                              void* d_out, int out_size, void* d_ws, size_t ws_size,
                              hipStream_t stream) {
  const float* x       = (const float*)d_in[0];
  const float* input_w = (const float*)d_in[1];
  const float* input_b = (const float*)d_in[2];
  const float* Wqkv    = (const float*)d_in[3];
  const float* bqkv    = (const float*)d_in[4];
  const float* Wo      = (const float*)d_in[5];
  const float* bo      = (const float*)d_in[6];
  const float* ln1_g   = (const float*)d_in[7];
  const float* ln1_b   = (const float*)d_in[8];
  const float* W1      = (const float*)d_in[9];
  const float* b1      = (const float*)d_in[10];
  const float* W2      = (const float*)d_in[11];
  const float* b2      = (const float*)d_in[12];
  const float* ln2_g   = (const float*)d_in[13];
  const float* ln2_b   = (const float*)d_in[14];
  const float* out_w   = (const float*)d_in[15];
  const float* out_b   = (const float*)d_in[16];
  float* out = (float*)d_out;
  float* ws  = (float*)d_ws;

  hipLaunchKernelGGL(precompute_kernel, dim3(2), dim3(256), 0, stream,
                     Wqkv, bqkv, Wo, bo, ws);
  hipLaunchKernelGGL(trm2_kernel, dim3(1024), dim3(256), 0, stream,
                     x, input_w, input_b, W1, b1, W2, b2, ln1_g, ln1_b,
                     ln2_g, ln2_b, out_w, out_b, ws, out);
}

// Round 4
// 139.225 us; speedup vs baseline: 2.6346x; 1.3851x over previous
//
#include <hip/hip_runtime.h>

// TinyRecursiveModel fused kernel, v4.
// = v3 structure (padded LDS, dual 16-row chains per wave, barrier-free
//   recurrence, W_vo folded via precompute) with RNE bf16 packing restored
//   (v3's v_cvt_pk_bf16_f32 is not RNE -> 0.037 absmax fail).
// Pack = v_bfe + v_add3 per float + one v_perm_b32 per pair (5 VALU/pair).

using bf16x8 = __attribute__((ext_vector_type(8))) short;
using f32x4  = __attribute__((ext_vector_type(4))) float;

#define DI __device__ __forceinline__

namespace {

constexpr int RS = 144;   // LDS row stride bytes: 64 bf16 (128B) + 16B pad
constexpr float EPS = 1e-5f;

DI unsigned rne1(float x) {           // f32 -> bf16-in-high-16, RNE
  unsigned u = __float_as_uint(x);
  return u + 0x7fffu + ((u >> 16) & 1u);
}
DI unsigned pack_bf2(float a, float b) {  // (hi(b)<<16)|hi(a)
  return __builtin_amdgcn_perm(rne1(b), rne1(a), 0x07060302u);
}

DI bf16x8 cvt8(f32x4 a, f32x4 b) {
  union { unsigned u[4]; bf16x8 h; } r;
  r.u[0] = pack_bf2(a[0], a[1]); r.u[1] = pack_bf2(a[2], a[3]);
  r.u[2] = pack_bf2(b[0], b[1]); r.u[3] = pack_bf2(b[2], b[3]);
  return r.h;
}

DI void wavefence() {
  __builtin_amdgcn_fence(__ATOMIC_SEQ_CST, "wavefront");  // compiler ordering
  asm volatile("s_waitcnt lgkmcnt(0)");                   // HW drain (no clobber)
}

struct WFrag { bf16x8 f[4][2]; };  // [tp][kstep] A-frags of a 64x64 matrix

DI WFrag loadW(const float* W, int l15, int g) {  // f32 row-major 64x64 -> frags
  WFrag w;
#pragma unroll
  for (int tp = 0; tp < 4; ++tp)
#pragma unroll
    for (int s = 0; s < 2; ++s) {
      const float* p = W + (16 * tp + l15) * 64 + 32 * s + 8 * g;
      w.f[tp][s] = cvt8(*(const f32x4*)p, *(const f32x4*)(p + 4));
    }
  return w;
}

DI f32x4 mfma(bf16x8 a, bf16x8 b, f32x4 c) {
  return __builtin_amdgcn_mfma_f32_16x16x32_bf16(a, b, c, 0, 0, 0);
}

DI void mm_reg(const WFrag& w, bf16x8 b0, bf16x8 b1, f32x4 (&acc)[4]) {
#pragma unroll
  for (int tp = 0; tp < 4; ++tp) {
    acc[tp] = mfma(w.f[tp][0], b0, acc[tp]);
    acc[tp] = mfma(w.f[tp][1], b1, acc[tp]);
  }
}

// abase = mat + l15*RS + 16*g  (A row = 16*tp + l15, k-halves at +0 / +64)
DI void mm_lds(const char* abase, bf16x8 b0, bf16x8 b1, f32x4 (&acc)[4]) {
#pragma unroll
  for (int tp = 0; tp < 4; ++tp) {
    bf16x8 a0 = *(const bf16x8*)(abase + tp * 16 * RS);
    bf16x8 a1 = *(const bf16x8*)(abase + tp * 16 * RS + 64);
    acc[tp] = mfma(a0, b0, acc[tp]);
    acc[tp] = mfma(a1, b1, acc[tp]);
  }
}

template <bool RELU>
DI void wrreg(char* wr, const f32x4 (&v)[4]) {  // wr = region + l15*RS + 8*g
#pragma unroll
  for (int tp = 0; tp < 4; ++tp) {
    float x0 = v[tp][0], x1 = v[tp][1], x2 = v[tp][2], x3 = v[tp][3];
    if (RELU) {
      x0 = fmaxf(x0, 0.f); x1 = fmaxf(x1, 0.f);
      x2 = fmaxf(x2, 0.f); x3 = fmaxf(x3, 0.f);
    }
    uint2 p;
    p.x = pack_bf2(x0, x1);
    p.y = pack_bf2(x2, x3);
    *(uint2*)(wr + 32 * tp) = p;
  }
}

DI void rdreg(const char* rd, bf16x8& b0, bf16x8& b1) {  // rd = region + l15*RS + 16*g
  b0 = *(const bf16x8*)rd;
  b1 = *(const bf16x8*)(rd + 64);
}

DI void addvec(const float* vec, int g, f32x4 (&a)[4]) {
#pragma unroll
  for (int tp = 0; tp < 4; ++tp)
    a[tp] += *(const f32x4*)(vec + 16 * tp + 4 * g);
}

// gb: gamma at +0, beta at +64 (floats)
DI void lnorm(const f32x4 (&a)[4], const float* gb, int g, f32x4 (&h)[4]) {
  float s = 0.f, q = 0.f;
#pragma unroll
  for (int tp = 0; tp < 4; ++tp)
#pragma unroll
    for (int r = 0; r < 4; ++r) { float x = a[tp][r]; s += x; q = fmaf(x, x, q); }
  s += __shfl_xor(s, 16); q += __shfl_xor(q, 16);
  s += __shfl_xor(s, 32); q += __shfl_xor(q, 32);
  float mean = s * 0.015625f;
  float var  = fmaf(q, 0.015625f, -mean * mean);
  float rs   = rsqrtf(var + EPS);
#pragma unroll
  for (int tp = 0; tp < 4; ++tp) {
    f32x4 gg = *(const f32x4*)(gb + 16 * tp + 4 * g);
    f32x4 bb = *(const f32x4*)(gb + 64 + 16 * tp + 4 * g);
#pragma unroll
    for (int r = 0; r < 4; ++r)
      h[tp][r] = fmaf((a[tp][r] - mean) * rs, gg[r], bb[r]);
  }
}

struct alignas(16) Smem {
  char  mats[4][64 * RS];        // W1 l0, W1 l1, W2 l0, W2 l1 (bf16, padded rows)
  float params[2 * 7 * 64];      // [layer][bvo,b1,b2,g1,be1,g2,be2][64]
  char  region[4][2][16 * RS];   // [wave][chain] activation staging
};

DI void do_layer(f32x4 (&hA)[4], f32x4 (&hB)[4], const WFrag& wvo,
                 const char* w1b, const char* w2b, const float* prm,
                 const char* rdA, char* wrA, const char* rdB, char* wrB, int g) {
  bf16x8 b0A, b1A, b0B, b1B;
  f32x4 aA[4], aB[4];
  // ---- P1: a = h + W_vo@h + b_vo ; h = LN1(a) ----
  rdreg(rdA, b0A, b1A); rdreg(rdB, b0B, b1B);
#pragma unroll
  for (int tp = 0; tp < 4; ++tp) { aA[tp] = hA[tp]; aB[tp] = hB[tp]; }
  mm_reg(wvo, b0A, b1A, aA);
  mm_reg(wvo, b0B, b1B, aB);
  addvec(prm, g, aA); addvec(prm, g, aB);
  lnorm(aA, prm + 192, g, hA);
  lnorm(aB, prm + 192, g, hB);
  wrreg<false>(wrA, hA); wrreg<false>(wrB, hB);
  wavefence();
  // ---- P2: t = relu(W1@h + b1) ----
  rdreg(rdA, b0A, b1A); rdreg(rdB, b0B, b1B);
#pragma unroll
  for (int tp = 0; tp < 4; ++tp) { aA[tp] = f32x4{0, 0, 0, 0}; aB[tp] = f32x4{0, 0, 0, 0}; }
  mm_lds(w1b, b0A, b1A, aA);
  mm_lds(w1b, b0B, b1B, aB);
  addvec(prm + 64, g, aA); addvec(prm + 64, g, aB);
  wrreg<true>(wrA, aA); wrreg<true>(wrB, aB);
  wavefence();
  // ---- P3: a = h + W2@t + b2 ; h = LN2(a) ----
  rdreg(rdA, b0A, b1A); rdreg(rdB, b0B, b1B);
#pragma unroll
  for (int tp = 0; tp < 4; ++tp) { aA[tp] = hA[tp]; aB[tp] = hB[tp]; }
  mm_lds(w2b, b0A, b1A, aA);
  mm_lds(w2b, b0B, b1B, aB);
  addvec(prm + 128, g, aA); addvec(prm + 128, g, aB);
  lnorm(aA, prm + 320, g, hA);
  lnorm(aB, prm + 320, g, hB);
  wrreg<false>(wrA, hA); wrreg<false>(wrB, hB);
  wavefence();
}

// ---------- precompute: W_vo = Wo @ Wv, b_vo = Wo @ bv + bo ----------
__global__ __launch_bounds__(256) void precompute_kernel(
    const float* __restrict__ Wqkv, const float* __restrict__ bqkv,
    const float* __restrict__ Wo, const float* __restrict__ bo,
    float* __restrict__ ws) {
  __shared__ float wv[4096];
  __shared__ float wo[4096];
  const int l = blockIdx.x;
  const float* Wv  = Wqkv + l * (192 * 64) + 128 * 64;
  const float* WoL = Wo + l * 4096;
  for (int e = threadIdx.x; e < 4096; e += 256) { wv[e] = Wv[e]; wo[e] = WoL[e]; }
  __syncthreads();
  float* wvo = ws + l * 4096;
  const int i = threadIdx.x >> 2, j0 = (threadIdx.x & 3) * 16;
  float acc[16];
#pragma unroll
  for (int jj = 0; jj < 16; ++jj) acc[jj] = 0.f;
  for (int k = 0; k < 64; ++k) {
    float a = wo[i * 64 + k];
#pragma unroll
    for (int jj = 0; jj < 16; ++jj) acc[jj] = fmaf(a, wv[k * 64 + j0 + jj], acc[jj]);
  }
#pragma unroll
  for (int jj = 0; jj < 16; ++jj) wvo[i * 64 + j0 + jj] = acc[jj];
  if (threadIdx.x < 64) {
    const int i2 = threadIdx.x;
    const float* bv = bqkv + l * 192 + 128;
    float s = bo[l * 64 + i2];
    for (int k = 0; k < 64; ++k) s = fmaf(wo[i2 * 64 + k], bv[k], s);
    ws[2 * 4096 + l * 64 + i2] = s;
  }
}

// ---------- main fused kernel ----------
__global__ __launch_bounds__(256, 2) void trm4_kernel(
    const float* __restrict__ x, const float* __restrict__ input_w,
    const float* __restrict__ input_b, const float* __restrict__ W1,
    const float* __restrict__ b1, const float* __restrict__ W2,
    const float* __restrict__ b2, const float* __restrict__ ln1_g,
    const float* __restrict__ ln1_b, const float* __restrict__ ln2_g,
    const float* __restrict__ ln2_b, const float* __restrict__ out_w,
    const float* __restrict__ out_b, const float* __restrict__ ws,
    float* __restrict__ out) {
  __shared__ Smem sm;
  const int tid = threadIdx.x;
  const int w = tid >> 6, lane = tid & 63;
  const int l15 = lane & 15, g = lane >> 4;
  const int row0 = blockIdx.x * 128 + w * 32;   // chain A rows row0.., B rows row0+16..

  // ---- stage W1/W2 (both layers) as bf16 into padded LDS ----
  {
    const float* srcs[4] = {W1, W1 + 4096, W2, W2 + 4096};
#pragma unroll
    for (int m = 0; m < 4; ++m) {
      char* dst = sm.mats[m];
      const float* src = srcs[m];
      for (int e = tid; e < 512; e += 256) {
        int row = e >> 3, c8 = (e & 7) * 8;
        const float* p = src + row * 64 + c8;
        *(bf16x8*)(dst + row * RS + 2 * c8) =
            cvt8(*(const f32x4*)p, *(const f32x4*)(p + 4));
      }
    }
  }
  // ---- stage per-layer param vectors ----
  for (int e = tid; e < 896; e += 256) {
    int l = e / 448, r = e % 448, v = r >> 6, j = r & 63;
    const float* src;
    switch (v) {
      case 0:  src = ws + 2 * 4096 + l * 64; break;  // b_vo
      case 1:  src = b1 + l * 64; break;
      case 2:  src = b2 + l * 64; break;
      case 3:  src = ln1_g + l * 64; break;
      case 4:  src = ln1_b + l * 64; break;
      case 5:  src = ln2_g + l * 64; break;
      default: src = ln2_b + l * 64; break;
    }
    sm.params[l * 448 + v * 64 + j] = src[j];
  }

  // ---- W_vo(l0,l1) fragments in registers ----
  WFrag wvo0 = loadW(ws, l15, g);
  WFrag wvo1 = loadW(ws + 4096, l15, g);

  // ---- per-lane LDS pointers (hoisted; all later accesses are base+imm) ----
  char* regA = sm.region[w][0];
  char* regB = sm.region[w][1];
  const int roff_r = l15 * RS + 16 * g;
  const int roff_w = l15 * RS + 8 * g;
  const char* rdA = regA + roff_r;  char* wrA = regA + roff_w;
  const char* rdB = regB + roff_r;  char* wrB = regB + roff_w;
  const char* w1b0 = sm.mats[0] + roff_r;
  const char* w1b1 = sm.mats[1] + roff_r;
  const char* w2b0 = sm.mats[2] + roff_r;
  const char* w2b1 = sm.mats[3] + roff_r;

  // ---- input projection: h = x @ input_w^T + input_b (K=200) ----
  f32x4 hA[4], hB[4];
#pragma unroll
  for (int tp = 0; tp < 4; ++tp) {
    f32x4 ib = *(const f32x4*)(input_b + 16 * tp + 4 * g);
    hA[tp] = ib; hB[tp] = ib;
  }
  {
    const float* xA = x + (size_t)(row0 + l15) * 200;
    const float* xB = xA + 16 * 200;
    const f32x4 zero = {0.f, 0.f, 0.f, 0.f};
    for (int s7 = 0; s7 < 7; ++s7) {
      int kb = 32 * s7 + 8 * g;
      bool v0 = kb < 200;
      f32x4 xa0 = v0 ? *(const f32x4*)(xA + kb) : zero;
      f32x4 xa1 = v0 ? *(const f32x4*)(xA + kb + 4) : zero;
      f32x4 xb0 = v0 ? *(const f32x4*)(xB + kb) : zero;
      f32x4 xb1 = v0 ? *(const f32x4*)(xB + kb + 4) : zero;
      bf16x8 bfA = cvt8(xa0, xa1);
      bf16x8 bfB = cvt8(xb0, xb1);
#pragma unroll
      for (int tp = 0; tp < 4; ++tp) {
        const float* wr = input_w + (16 * tp + l15) * 200;
        f32x4 wa = v0 ? *(const f32x4*)(wr + kb) : zero;
        f32x4 wb = v0 ? *(const f32x4*)(wr + kb + 4) : zero;
        bf16x8 af = cvt8(wa, wb);
        hA[tp] = mfma(af, bfA, hA[tp]);
        hB[tp] = mfma(af, bfB, hB[tp]);
      }
    }
  }
  wrreg<false>(wrA, hA);
  wrreg<false>(wrB, hB);
  wavefence();
  __syncthreads();  // mats/params staged; the only block barrier

  // ---- recurrence: 16 steps x 2 layers, barrier-free ----
#pragma unroll 1
  for (int step = 0; step < 16; ++step) {
    do_layer(hA, hB, wvo0, w1b0, w2b0, sm.params,       rdA, wrA, rdB, wrB, g);
    do_layer(hA, hB, wvo1, w1b1, w2b1, sm.params + 448, rdA, wrA, rdB, wrB, g);
  }

  // ---- out = h . out_w + out_b ----
  float pA = 0.f, pB = 0.f;
#pragma unroll
  for (int tp = 0; tp < 4; ++tp) {
    f32x4 ow = *(const f32x4*)(out_w + 16 * tp + 4 * g);
#pragma unroll
    for (int r = 0; r < 4; ++r) {
      pA = fmaf(hA[tp][r], ow[r], pA);
      pB = fmaf(hB[tp][r], ow[r], pB);
    }
  }
  pA += __shfl_xor(pA, 16); pA += __shfl_xor(pA, 32);
  pB += __shfl_xor(pB, 16); pB += __shfl_xor(pB, 32);
  if (lane < 16) {
    float ob = out_b[0];
    out[row0 + l15]      = pA + ob;
    out[row0 + 16 + l15] = pB + ob;
  }
}

}  // namespace

extern "C" void kernel_launch(void* const* d_in, const int* in_sizes, int n_in,
                              void* d_out, int out_size, void* d_ws, size_t ws_size,
                              hipStream_t stream) {
  const float* x       = (const float*)d_in[0];
  const float* input_w = (const float*)d_in[1];
  const float* input_b = (const float*)d_in[2];
  const float* Wqkv    = (const float*)d_in[3];
  const float* bqkv    = (const float*)d_in[4];
  const float* Wo      = (const float*)d_in[5];
  const float* bo      = (const float*)d_in[6];
  const float* ln1_g   = (const float*)d_in[7];
  const float* ln1_b   = (const float*)d_in[8];
  const float* W1      = (const float*)d_in[9];
  const float* b1      = (const float*)d_in[10];
  const float* W2      = (const float*)d_in[11];
  const float* b2      = (const float*)d_in[12];
  const float* ln2_g   = (const float*)d_in[13];
  const float* ln2_b   = (const float*)d_in[14];
  const float* out_w   = (const float*)d_in[15];
  const float* out_b   = (const float*)d_in[16];
  float* out = (float*)d_out;
  float* ws  = (float*)d_ws;

  hipLaunchKernelGGL(precompute_kernel, dim3(2), dim3(256), 0, stream,
                     Wqkv, bqkv, Wo, bo, ws);
  hipLaunchKernelGGL(trm4_kernel, dim3(512), dim3(256), 0, stream,
                     x, input_w, input_b, W1, b1, W2, b2, ln1_g, ln1_b,
                     ln2_g, ln2_b, out_w, out_b, ws, out);
}

// Round 5
// 117.334 us; speedup vs baseline: 3.1262x; 1.1866x over previous
//
#include <hip/hip_runtime.h>

// TinyRecursiveModel fused kernel, v5.
// vs v4: (1) fp16 MFMA path (8x less rounding error than bf16 -> margin;
// cheaper RNE pack via v_cvt_f16_f32 + v_pack_b32_f16), (2) activation
// redistribution via permlane16/32_swap butterfly (8 VALU ops) instead of
// LDS write/fence/read per phase -> zero LDS traffic and zero fences in the
// 32-layer recurrence, (3) lnorm on 2-fma form with permlane reductions.

using f16x8 = __attribute__((ext_vector_type(8))) _Float16;
using f32x4 = __attribute__((ext_vector_type(4))) float;

#define DI __device__ __forceinline__

namespace {

constexpr int RS = 144;   // LDS row stride bytes for weight mats (128B + 16B pad)
constexpr float EPS = 1e-5f;

DI unsigned packh2(float a, float b) {  // two f32 -> packed f16 pair (RNE)
  _Float16 lo = (_Float16)a, hi = (_Float16)b;
  unsigned short ul = __builtin_bit_cast(unsigned short, lo);
  unsigned short uh = __builtin_bit_cast(unsigned short, hi);
  return ((unsigned)uh << 16) | (unsigned)ul;
}

DI f16x8 cvt8h(f32x4 a, f32x4 b) {
  f16x8 r;
  r[0] = (_Float16)a[0]; r[1] = (_Float16)a[1];
  r[2] = (_Float16)a[2]; r[3] = (_Float16)a[3];
  r[4] = (_Float16)b[0]; r[5] = (_Float16)b[1];
  r[6] = (_Float16)b[2]; r[7] = (_Float16)b[3];
  return r;
}

DI unsigned pkmax0(unsigned t) {  // packed f16 relu
  unsigned r;
  asm("v_pk_max_f16 %0, %1, 0" : "=v"(r) : "v"(t));
  return r;
}

// ---- lane-group swaps (g = lane>>4; bit4/bit5 butterflies) ----
DI void swap16(unsigned& a, unsigned& b) {
#if __has_builtin(__builtin_amdgcn_permlane16_swap)
  auto r = __builtin_amdgcn_permlane16_swap(a, b, false, false);
  a = r[0]; b = r[1];
#else
  unsigned ax = (unsigned)__shfl_xor((int)a, 16);
  unsigned bx = (unsigned)__shfl_xor((int)b, 16);
  bool odd = (threadIdx.x & 16) != 0;
  unsigned na = odd ? bx : a;   // odd rows receive partner's b
  unsigned nb = odd ? b : ax;   // even rows receive partner's a
  a = na; b = nb;
#endif
}
DI void swap32(unsigned& a, unsigned& b) {
#if __has_builtin(__builtin_amdgcn_permlane32_swap)
  auto r = __builtin_amdgcn_permlane32_swap(a, b, false, false);
  a = r[0]; b = r[1];
#else
  unsigned ax = (unsigned)__shfl_xor((int)a, 32);
  unsigned bx = (unsigned)__shfl_xor((int)b, 32);
  bool hi = (threadIdx.x & 32) != 0;
  unsigned na = hi ? bx : a;
  unsigned nb = hi ? b : ax;
  a = na; b = nb;
#endif
}

DI float reduce4(float x) {  // sum across the 4 g-groups (same l15)
  unsigned a = __builtin_bit_cast(unsigned, x), b = a;
  swap16(a, b);
  float x1 = __builtin_bit_cast(float, a) + __builtin_bit_cast(float, b);
  unsigned c = __builtin_bit_cast(unsigned, x1), d = c;
  swap32(c, d);
  return __builtin_bit_cast(float, c) + __builtin_bit_cast(float, d);
}

union BU {  // u[0..3] = b0 frag (k 0..31), u[4..7] = b1 frag (k 32..63)
  unsigned u[8];
  struct { f16x8 b0, b1; } f;
};

// pack acc (D layout) into P[tp][j] u32s: flat[2tp+j] = features 16tp+4g+2j,+1
template <bool RELU>
DI void packacc(const f32x4 (&acc)[4], BU& o) {
#pragma unroll
  for (int tp = 0; tp < 4; ++tp) {
    unsigned p0 = packh2(acc[tp][0], acc[tp][1]);
    unsigned p1 = packh2(acc[tp][2], acc[tp][3]);
    if (RELU) { p0 = pkmax0(p0); p1 = pkmax0(p1); }
    o.u[2 * tp + 0] = p0;
    o.u[2 * tp + 1] = p1;
  }
}

// butterfly: after this, o.u[0..3]=b0 (m=4g'..4g'+3), o.u[4..7]=b1
DI void exchange(BU& o) {
  swap32(o.u[0], o.u[2]); swap32(o.u[1], o.u[3]);
  swap32(o.u[4], o.u[6]); swap32(o.u[5], o.u[7]);
  swap16(o.u[0], o.u[2]); swap16(o.u[1], o.u[3]);
  swap16(o.u[4], o.u[6]); swap16(o.u[5], o.u[7]);
}

struct WFrag { f16x8 f[4][2]; };  // [tp][khalf] A-frags of a 64x64 matrix

DI WFrag loadW(const float* W, int l15, int g) {  // f32 row-major 64x64
  WFrag w;
#pragma unroll
  for (int tp = 0; tp < 4; ++tp)
#pragma unroll
    for (int s = 0; s < 2; ++s) {
      const float* p = W + (16 * tp + l15) * 64 + 32 * s + 8 * g;
      w.f[tp][s] = cvt8h(*(const f32x4*)p, *(const f32x4*)(p + 4));
    }
  return w;
}

DI f32x4 mfma(f16x8 a, f16x8 b, f32x4 c) {
  return __builtin_amdgcn_mfma_f32_16x16x32_f16(a, b, c, 0, 0, 0);
}

// gb: gamma at +0, beta at +64 floats. 2-fma apply form.
DI void lnorm(const f32x4 (&a)[4], const float* gb, int g, f32x4 (&h)[4]) {
  float s = 0.f, q = 0.f;
#pragma unroll
  for (int tp = 0; tp < 4; ++tp)
#pragma unroll
    for (int r = 0; r < 4; ++r) { float x = a[tp][r]; s += x; q = fmaf(x, x, q); }
  s = reduce4(s); q = reduce4(q);
  float mean = s * 0.015625f;
  float var  = fmaf(q, 0.015625f, -mean * mean);
  float rs   = rsqrtf(var + EPS);
  float u    = -mean * rs;
  const f32x4* gv = (const f32x4*)gb;
#pragma unroll
  for (int tp = 0; tp < 4; ++tp) {
    f32x4 gg = gv[4 * tp + g];
    f32x4 bb = gv[16 + 4 * tp + g];
#pragma unroll
    for (int r = 0; r < 4; ++r)
      h[tp][r] = fmaf(fmaf(a[tp][r], rs, u), gg[r], bb[r]);
  }
}

struct alignas(16) Smem {
  char  mats[4][64 * RS];    // W1 l0, W1 l1, W2 l0, W2 l1 (f16, padded rows)
  float params[2 * 7 * 64];  // [layer][bvo,b1,b2,g1,be1,g2,be2][64]
};

// One transformer layer for both chains. b-frags arrive in bA/bB; leaves
// next-layer P1 b-frags in bA/bB.
DI void do_layer(f32x4 (&hA)[4], f32x4 (&hB)[4], BU& bA, BU& bB,
                 const WFrag& wvo, const char* w1b, const char* w2b,
                 const float* prm, int g) {
  const f32x4* pv = (const f32x4*)prm;
  f32x4 aA[4], aB[4];
  // ---- P1: a = h + W_vo@h + b_vo ; h = LN1(a) ----
#pragma unroll
  for (int tp = 0; tp < 4; ++tp) {
    aA[tp] = mfma(wvo.f[tp][1], bA.f.b1, mfma(wvo.f[tp][0], bA.f.b0, hA[tp]));
    aB[tp] = mfma(wvo.f[tp][1], bB.f.b1, mfma(wvo.f[tp][0], bB.f.b0, hB[tp]));
    f32x4 bv = pv[4 * tp + g];
    aA[tp] += bv; aB[tp] += bv;
  }
  lnorm(aA, prm + 192, g, hA);
  lnorm(aB, prm + 192, g, hB);
  packacc<false>(hA, bA); packacc<false>(hB, bB);
  exchange(bA); exchange(bB);
  // ---- P2: t = relu(W1@h + b1) ----
#pragma unroll
  for (int tp = 0; tp < 4; ++tp) {
    f16x8 a0 = *(const f16x8*)(w1b + tp * 16 * RS);
    f16x8 a1 = *(const f16x8*)(w1b + tp * 16 * RS + 64);
    f32x4 cin = pv[16 + 4 * tp + g];
    aA[tp] = mfma(a1, bA.f.b1, mfma(a0, bA.f.b0, cin));
    aB[tp] = mfma(a1, bB.f.b1, mfma(a0, bB.f.b0, cin));
  }
  packacc<true>(aA, bA); packacc<true>(aB, bB);
  exchange(bA); exchange(bB);
  // ---- P3: a = h + W2@t + b2 ; h = LN2(a) ----
#pragma unroll
  for (int tp = 0; tp < 4; ++tp) {
    f16x8 a0 = *(const f16x8*)(w2b + tp * 16 * RS);
    f16x8 a1 = *(const f16x8*)(w2b + tp * 16 * RS + 64);
    aA[tp] = mfma(a1, bA.f.b1, mfma(a0, bA.f.b0, hA[tp]));
    aB[tp] = mfma(a1, bB.f.b1, mfma(a0, bB.f.b0, hB[tp]));
    f32x4 bv = pv[32 + 4 * tp + g];
    aA[tp] += bv; aB[tp] += bv;
  }
  lnorm(aA, prm + 320, g, hA);
  lnorm(aB, prm + 320, g, hB);
  packacc<false>(hA, bA); packacc<false>(hB, bB);
  exchange(bA); exchange(bB);
}

// ---------- precompute: W_vo = Wo @ Wv, b_vo = Wo @ bv + bo ----------
__global__ __launch_bounds__(256) void precompute_kernel(
    const float* __restrict__ Wqkv, const float* __restrict__ bqkv,
    const float* __restrict__ Wo, const float* __restrict__ bo,
    float* __restrict__ ws) {
  __shared__ float wv[4096];
  __shared__ float wo[4096];
  const int l = blockIdx.x;
  const float* Wv  = Wqkv + l * (192 * 64) + 128 * 64;
  const float* WoL = Wo + l * 4096;
  for (int e = threadIdx.x; e < 4096; e += 256) { wv[e] = Wv[e]; wo[e] = WoL[e]; }
  __syncthreads();
  float* wvo = ws + l * 4096;
  const int i = threadIdx.x >> 2, j0 = (threadIdx.x & 3) * 16;
  float acc[16];
#pragma unroll
  for (int jj = 0; jj < 16; ++jj) acc[jj] = 0.f;
  for (int k = 0; k < 64; ++k) {
    float a = wo[i * 64 + k];
#pragma unroll
    for (int jj = 0; jj < 16; ++jj) acc[jj] = fmaf(a, wv[k * 64 + j0 + jj], acc[jj]);
  }
#pragma unroll
  for (int jj = 0; jj < 16; ++jj) wvo[i * 64 + j0 + jj] = acc[jj];
  if (threadIdx.x < 64) {
    const int i2 = threadIdx.x;
    const float* bv = bqkv + l * 192 + 128;
    float s = bo[l * 64 + i2];
    for (int k = 0; k < 64; ++k) s = fmaf(wo[i2 * 64 + k], bv[k], s);
    ws[2 * 4096 + l * 64 + i2] = s;
  }
}

// ---------- main fused kernel ----------
__global__ __launch_bounds__(256, 2) void trm5_kernel(
    const float* __restrict__ x, const float* __restrict__ input_w,
    const float* __restrict__ input_b, const float* __restrict__ W1,
    const float* __restrict__ b1, const float* __restrict__ W2,
    const float* __restrict__ b2, const float* __restrict__ ln1_g,
    const float* __restrict__ ln1_b, const float* __restrict__ ln2_g,
    const float* __restrict__ ln2_b, const float* __restrict__ out_w,
    const float* __restrict__ out_b, const float* __restrict__ ws,
    float* __restrict__ out) {
  __shared__ Smem sm;
  const int tid = threadIdx.x;
  const int w = tid >> 6, lane = tid & 63;
  const int l15 = lane & 15, g = lane >> 4;
  const int row0 = blockIdx.x * 128 + w * 32;  // chain A: row0+l15, B: +16

  // ---- stage W1/W2 (both layers) as f16 into padded LDS ----
  {
    const float* srcs[4] = {W1, W1 + 4096, W2, W2 + 4096};
#pragma unroll
    for (int m = 0; m < 4; ++m) {
      char* dst = sm.mats[m];
      const float* src = srcs[m];
      for (int e = tid; e < 512; e += 256) {
        int row = e >> 3, c8 = (e & 7) * 8;
        const float* p = src + row * 64 + c8;
        *(f16x8*)(dst + row * RS + 2 * c8) =
            cvt8h(*(const f32x4*)p, *(const f32x4*)(p + 4));
      }
    }
  }
  // ---- stage per-layer param vectors (fp32) ----
  for (int e = tid; e < 896; e += 256) {
    int l = e / 448, r = e % 448, v = r >> 6, j = r & 63;
    const float* src;
    switch (v) {
      case 0:  src = ws + 2 * 4096 + l * 64; break;  // b_vo
      case 1:  src = b1 + l * 64; break;
      case 2:  src = b2 + l * 64; break;
      case 3:  src = ln1_g + l * 64; break;
      case 4:  src = ln1_b + l * 64; break;
      case 5:  src = ln2_g + l * 64; break;
      default: src = ln2_b + l * 64; break;
    }
    sm.params[l * 448 + v * 64 + j] = src[j];
  }

  // ---- W_vo(l0,l1) fragments in registers ----
  WFrag wvo0 = loadW(ws, l15, g);
  WFrag wvo1 = loadW(ws + 4096, l15, g);

  const char* w1b0 = sm.mats[0] + l15 * RS + 16 * g;
  const char* w1b1 = sm.mats[1] + l15 * RS + 16 * g;
  const char* w2b0 = sm.mats[2] + l15 * RS + 16 * g;
  const char* w2b1 = sm.mats[3] + l15 * RS + 16 * g;

  // ---- input projection: h = x @ input_w^T + input_b (K=200) ----
  f32x4 hA[4], hB[4];
#pragma unroll
  for (int tp = 0; tp < 4; ++tp) {
    f32x4 ib = *(const f32x4*)(input_b + 16 * tp + 4 * g);
    hA[tp] = ib; hB[tp] = ib;
  }
  {
    const float* xA = x + (size_t)(row0 + l15) * 200;
    const float* xB = xA + 16 * 200;
    const f32x4 zero = {0.f, 0.f, 0.f, 0.f};
    for (int s7 = 0; s7 < 7; ++s7) {
      int kb = 32 * s7 + 8 * g;
      bool v0 = kb < 200;
      f32x4 xa0 = v0 ? *(const f32x4*)(xA + kb) : zero;
      f32x4 xa1 = v0 ? *(const f32x4*)(xA + kb + 4) : zero;
      f32x4 xb0 = v0 ? *(const f32x4*)(xB + kb) : zero;
      f32x4 xb1 = v0 ? *(const f32x4*)(xB + kb + 4) : zero;
      f16x8 bfA = cvt8h(xa0, xa1);
      f16x8 bfB = cvt8h(xb0, xb1);
#pragma unroll
      for (int tp = 0; tp < 4; ++tp) {
        const float* wr = input_w + (16 * tp + l15) * 200;
        f32x4 wa = v0 ? *(const f32x4*)(wr + kb) : zero;
        f32x4 wb = v0 ? *(const f32x4*)(wr + kb + 4) : zero;
        f16x8 af = cvt8h(wa, wb);
        hA[tp] = mfma(af, bfA, hA[tp]);
        hB[tp] = mfma(af, bfB, hB[tp]);
      }
    }
  }
  BU bA, bB;
  packacc<false>(hA, bA); packacc<false>(hB, bB);
  exchange(bA); exchange(bB);
  __syncthreads();  // mats/params staged; the only block barrier

  // ---- recurrence: 16 steps x 2 layers, no LDS writes, no fences ----
#pragma unroll 1
  for (int step = 0; step < 16; ++step) {
    do_layer(hA, hB, bA, bB, wvo0, w1b0, w2b0, sm.params,       g);
    do_layer(hA, hB, bA, bB, wvo1, w1b1, w2b1, sm.params + 448, g);
  }

  // ---- out = h . out_w + out_b ----
  float pA = 0.f, pB = 0.f;
#pragma unroll
  for (int tp = 0; tp < 4; ++tp) {
    f32x4 ow = *(const f32x4*)(out_w + 16 * tp + 4 * g);
#pragma unroll
    for (int r = 0; r < 4; ++r) {
      pA = fmaf(hA[tp][r], ow[r], pA);
      pB = fmaf(hB[tp][r], ow[r], pB);
    }
  }
  pA += __shfl_xor(pA, 16); pA += __shfl_xor(pA, 32);
  pB += __shfl_xor(pB, 16); pB += __shfl_xor(pB, 32);
  if (lane < 16) {
    float ob = out_b[0];
    out[row0 + l15]      = pA + ob;
    out[row0 + 16 + l15] = pB + ob;
  }
}

}  // namespace

extern "C" void kernel_launch(void* const* d_in, const int* in_sizes, int n_in,
                              void* d_out, int out_size, void* d_ws, size_t ws_size,
                              hipStream_t stream) {
  const float* x       = (const float*)d_in[0];
  const float* input_w = (const float*)d_in[1];
  const float* input_b = (const float*)d_in[2];
  const float* Wqkv    = (const float*)d_in[3];
  const float* bqkv    = (const float*)d_in[4];
  const float* Wo      = (const float*)d_in[5];
  const float* bo      = (const float*)d_in[6];
  const float* ln1_g   = (const float*)d_in[7];
  const float* ln1_b   = (const float*)d_in[8];
  const float* W1      = (const float*)d_in[9];
  const float* b1      = (const float*)d_in[10];
  const float* W2      = (const float*)d_in[11];
  const float* b2      = (const float*)d_in[12];
  const float* ln2_g   = (const float*)d_in[13];
  const float* ln2_b   = (const float*)d_in[14];
  const float* out_w   = (const float*)d_in[15];
  const float* out_b   = (const float*)d_in[16];
  float* out = (float*)d_out;
  float* ws  = (float*)d_ws;

  hipLaunchKernelGGL(precompute_kernel, dim3(2), dim3(256), 0, stream,
                     Wqkv, bqkv, Wo, bo, ws);
  hipLaunchKernelGGL(trm5_kernel, dim3(512), dim3(256), 0, stream,
                     x, input_w, input_b, W1, b1, W2, b2, ln1_g, ln1_b,
                     ln2_g, ln2_b, out_w, out_b, ws, out);
}